// Round 1
// baseline (149.877 us; speedup 1.0000x reference)
//
#include <hip/hip_runtime.h>

#define B_N 8192
#define D_N 1024
#define C_N 1024
#define BM 256
#define BN 128
#define BK 64

typedef __attribute__((ext_vector_type(8))) __bf16 bf16x8;
typedef __attribute__((ext_vector_type(16))) float floatx16;

__device__ inline unsigned short f2bf(float f) {
  union { float f; unsigned int u; } cv; cv.f = f;
  unsigned int b = cv.u;
  unsigned int r = (b + 0x7FFFu + ((b >> 16) & 1u)) >> 16;  // RNE
  return (unsigned short)r;
}
__device__ inline float d4(const float4 a) {
  return a.x * a.x + a.y * a.y + a.z * a.z + a.w * a.w;
}
__device__ inline ushort4 pk4(const float4 v, const float s) {
  ushort4 u;
  u.x = f2bf(v.x * s); u.y = f2bf(v.y * s);
  u.z = f2bf(v.z * s); u.w = f2bf(v.w * s);
  return u;
}

// ---------------------------------------------------------------------------
// prep_kernel: unchanged (1024 fat blocks).
// ---------------------------------------------------------------------------
__global__ __launch_bounds__(256) void prep_kernel(
    const float* __restrict__ emb_i, const float* __restrict__ emb_j,
    const int* __restrict__ labels,
    unsigned short* __restrict__ z_j, unsigned short* __restrict__ proto,
    float* __restrict__ p2, float* __restrict__ out) {
  __shared__ float sx[4][8];
  __shared__ int list[8];
  __shared__ int scnt;

  const int t = threadIdx.x;
  const int lane = t & 63;
  const int wid = t >> 6;
  const int blk = blockIdx.x;

  if (t == 0) scnt = 0;
  if (blk == 0 && t == 0) out[0] = 0.0f;

#pragma unroll
  for (int it = 0; it < 2; ++it) {
    const int row = blk * 8 + it * 4 + wid;
    const float4* src = (const float4*)(emb_j + (size_t)row * D_N);
    const float4 v0 = src[lane], v1 = src[lane + 64];
    const float4 v2 = src[lane + 128], v3 = src[lane + 192];
    float ss = d4(v0) + d4(v1) + d4(v2) + d4(v3);
    for (int o = 32; o; o >>= 1) ss += __shfl_xor(ss, o, 64);
    const float inv = 1.0f / fmaxf(sqrtf(ss), 1e-12f);
    ushort4* dst = (ushort4*)(z_j + (size_t)row * D_N);
    dst[lane] = pk4(v0, inv);
    dst[lane + 64] = pk4(v1, inv);
    dst[lane + 128] = pk4(v2, inv);
    dst[lane + 192] = pk4(v3, inv);
  }

  const int c = blk;
  __syncthreads();
  const int4* lab4 = (const int4*)labels;
  for (int i = 0; i < 8; ++i) {
    const int q = i * 256 + t;
    const int4 L = lab4[q];
    const int base = q * 4;
    if (L.x == c) list[atomicAdd(&scnt, 1) & 7] = base;
    if (L.y == c) list[atomicAdd(&scnt, 1) & 7] = base + 1;
    if (L.z == c) list[atomicAdd(&scnt, 1) & 7] = base + 2;
    if (L.w == c) list[atomicAdd(&scnt, 1) & 7] = base + 3;
  }
  __syncthreads();

  const float* base = emb_i + wid * 256;
  float4 v[8];
  float ss[8];
#pragma unroll
  for (int k = 0; k < 8; ++k) {
    v[k] = ((const float4*)(base + (size_t)list[k] * D_N))[lane];
    ss[k] = d4(v[k]);
  }
#pragma unroll
  for (int k = 0; k < 8; ++k)
    for (int o = 32; o; o >>= 1) ss[k] += __shfl_xor(ss[k], o, 64);
  if (lane == 0) {
#pragma unroll
    for (int k = 0; k < 8; ++k) sx[wid][k] = ss[k];
  }
  __syncthreads();

  float4 a = make_float4(0.f, 0.f, 0.f, 0.f);
#pragma unroll
  for (int k = 0; k < 8; ++k) {
    const float tot = sx[0][k] + sx[1][k] + sx[2][k] + sx[3][k];
    const float iv = 1.0f / fmaxf(sqrtf(tot), 1e-12f);
    a.x += v[k].x * iv; a.y += v[k].y * iv;
    a.z += v[k].z * iv; a.w += v[k].w * iv;
  }
  a.x *= 0.125f; a.y *= 0.125f; a.z *= 0.125f; a.w *= 0.125f;

  float pp = d4(a);
  for (int o = 32; o; o >>= 1) pp += __shfl_xor(pp, o, 64);
  __syncthreads();
  if (lane == 0) sx[wid][0] = pp;
  __syncthreads();
  if (t == 0) p2[c] = sx[0][0] + sx[1][0] + sx[2][0] + sx[3][0];

  ((ushort4*)(proto + (size_t)c * D_N + wid * 256))[lane] = pk4(a, 1.0f);
}

// ---------------------------------------------------------------------------
// gemm_loss_kernel v4: 256x128 tile, BK=64, 512 threads (8 waves 4Mx2N,
// per-wave 64x64 = 2x2 of 32x32x16 MFMA). 3-deep LDS pipeline (3 x 48KB),
// counted s_waitcnt vmcnt(12) -- never drains to 0 in main loop (T3/T4).
// Raw s_barrier (no __syncthreads => no forced vmcnt(0) drain). setprio
// around MFMA cluster (T5). XOR chunk-swizzle both-sides (T2-style, same
// involution on global source and LDS read). Fused BCE epilogue unchanged.
// C/D layout (m74/m101): col=lane&31, row=(reg&3)+8*(reg>>2)+4*(lane>>5).
//
// Per-wave vmcnt ledger (6 global_load_lds per wave per stage):
//   prologue: s0,s1 issued            -> outstanding 12
//   iter kt<=13: issue s(kt+2) (->18); wait vmcnt(12) => s(kt) landed
//   kt=14: no issue; wait vmcnt(6)  => s14 landed
//   kt=15: wait vmcnt(0)            => s15 landed
// Buffer for K-tile j = j%3. stage(kt+2) at iter kt targets (kt+2)%3, which
// was last READ at iter kt-1; all waves passed iter kt-1's end barrier
// (after their lgkm-gated ds_reads) before issue => no overwrite race.
// ---------------------------------------------------------------------------
#define GLOAD(gp, lp)                                                        \
  __builtin_amdgcn_global_load_lds(                                          \
      (const __attribute__((address_space(1))) void*)(gp),                   \
      (__attribute__((address_space(3))) void*)(lp), 16, 0, 0)

__global__ __launch_bounds__(512) void gemm_loss_kernel(
    const unsigned short* __restrict__ Zj,   // [B,D] bf16
    const unsigned short* __restrict__ P,    // [C,D] bf16
    const float* __restrict__ p2,            // [C]
    const int* __restrict__ labels,          // [B]
    float* __restrict__ out) {               // scalar (zeroed by prep)
  // buffer = A(256x64) 32KB + B(128x64) 16KB = 24576 ushorts; x3 = 144KB
  __shared__ __align__(16) unsigned short lds[3 * 24576];
  __shared__ float sred[8];

  const int t = threadIdx.x;
  const int lane = t & 63;
  const int wid = t >> 6;
  const int wm = (wid >> 1) * 64;   // 4 waves in M: 0,64,128,192
  const int wn = (wid & 1) * 64;    // 2 waves in N: 0,64
  const int bm = blockIdx.x;
  const int bn = blockIdx.y;

  floatx16 acc[2][2];
#pragma unroll
  for (int i = 0; i < 2; ++i)
#pragma unroll
    for (int j = 0; j < 2; ++j)
      for (int r = 0; r < 16; ++r) acc[i][j][r] = 0.f;

  // --- staging addresses: pass = 512 thr x 16B = 8KB = 64 rows x 128B.
  // thread t -> row (t>>3) (+64 per pass), chunk slot t&7, fetching global
  // chunk (t&7)^(row&7). rows advance by 64 => row&7 invariant across passes.
  const int srow = t >> 3;
  const int g = (t & 7) ^ (srow & 7);
  const unsigned short* Ag = Zj + (size_t)(bm * BM + srow) * D_N + g * 8;
  const unsigned short* Bg = P + (size_t)(bn * BN + srow) * D_N + g * 8;
  unsigned short* const Al0 = (unsigned short*)lds + t * 8;
  unsigned short* const Bl0 = (unsigned short*)lds + 16384 + t * 8;

  // --- ds_read offsets within one buffer (ushort units), row stride BK=64
  const int ar0 = (wm + (lane & 31)) * BK;
  const int ar1 = ar0 + 32 * BK;
  const int br0 = 16384 + (wn + (lane & 31)) * BK;
  const int br1 = br0 + 32 * BK;
  const int h = lane >> 5;  // K-half selector
  const int q = lane & 7;   // row&7 for swizzle inverse

#define STAGE(bi, kt)                                                        \
  {                                                                          \
    const int _bo = (bi) * 24576;                                            \
    const int _k0 = (kt) * BK;                                               \
    GLOAD(Ag + (size_t)0 * 64 * D_N + _k0, Al0 + _bo + 0 * 4096);            \
    GLOAD(Ag + (size_t)1 * 64 * D_N + _k0, Al0 + _bo + 1 * 4096);            \
    GLOAD(Ag + (size_t)2 * 64 * D_N + _k0, Al0 + _bo + 2 * 4096);            \
    GLOAD(Ag + (size_t)3 * 64 * D_N + _k0, Al0 + _bo + 3 * 4096);            \
    GLOAD(Bg + (size_t)0 * 64 * D_N + _k0, Bl0 + _bo + 0 * 4096);            \
    GLOAD(Bg + (size_t)1 * 64 * D_N + _k0, Bl0 + _bo + 1 * 4096);            \
  }

#define COMPUTE(bi)                                                          \
  {                                                                          \
    const unsigned short* Lb = (const unsigned short*)lds + (bi) * 24576;    \
    _Pragma("unroll") for (int kk = 0; kk < 4; ++kk) {                       \
      const int swz = ((kk * 2 + h) ^ q) << 3;                               \
      bf16x8 a0 = *(const bf16x8*)(Lb + ar0 + swz);                          \
      bf16x8 a1 = *(const bf16x8*)(Lb + ar1 + swz);                          \
      bf16x8 b0 = *(const bf16x8*)(Lb + br0 + swz);                          \
      bf16x8 b1 = *(const bf16x8*)(Lb + br1 + swz);                          \
      acc[0][0] = __builtin_amdgcn_mfma_f32_32x32x16_bf16(a0, b0, acc[0][0], 0, 0, 0); \
      acc[0][1] = __builtin_amdgcn_mfma_f32_32x32x16_bf16(a0, b1, acc[0][1], 0, 0, 0); \
      acc[1][0] = __builtin_amdgcn_mfma_f32_32x32x16_bf16(a1, b0, acc[1][0], 0, 0, 0); \
      acc[1][1] = __builtin_amdgcn_mfma_f32_32x32x16_bf16(a1, b1, acc[1][1], 0, 0, 0); \
    }                                                                        \
  }

  // prologue: fill buffers 0 and 1 (K-tiles 0, 1)
  STAGE(0, 0);
  STAGE(1, 1);

  int cur = 0;
  for (int kt = 0; kt < 14; ++kt) {
    const int nb = (cur + 2 >= 3) ? (cur - 1) : (cur + 2);  // (kt+2)%3
    STAGE(nb, kt + 2);
    asm volatile("s_waitcnt vmcnt(12)" ::: "memory");
    __builtin_amdgcn_s_barrier();
    __builtin_amdgcn_sched_barrier(0);
    __builtin_amdgcn_s_setprio(1);
    COMPUTE(cur);
    __builtin_amdgcn_s_setprio(0);
    __builtin_amdgcn_sched_barrier(0);
    __builtin_amdgcn_s_barrier();
    cur = (cur == 2) ? 0 : cur + 1;
  }
  // kt = 14 (buffer 2)
  asm volatile("s_waitcnt vmcnt(6)" ::: "memory");
  __builtin_amdgcn_s_barrier();
  __builtin_amdgcn_sched_barrier(0);
  COMPUTE(cur);
  cur = (cur == 2) ? 0 : cur + 1;
  // kt = 15 (buffer 0)
  asm volatile("s_waitcnt vmcnt(0)" ::: "memory");
  __builtin_amdgcn_s_barrier();
  __builtin_amdgcn_sched_barrier(0);
  COMPUTE(cur);

  // epilogue: 32x32 C/D layout col=lane&31, row=(reg&3)+8*(reg>>2)+4*(lane>>5)
  const int colbase = bn * BN + wn + (lane & 31);
  float lsum = 0.f;
#pragma unroll
  for (int mb = 0; mb < 2; ++mb) {
    const int rowbase = bm * BM + wm + mb * 32 + 4 * h;
    int labv[16];
#pragma unroll
    for (int reg = 0; reg < 16; ++reg)
      labv[reg] = labels[rowbase + (reg & 3) + 8 * (reg >> 2)];
#pragma unroll
    for (int nb2 = 0; nb2 < 2; ++nb2) {
      const int col = colbase + nb2 * 32;
      const float p2c = p2[col];
#pragma unroll
      for (int reg = 0; reg < 16; ++reg) {
        const float dot = acc[mb][nb2][reg];
        const float d2 = 1.0f + p2c - 2.0f * dot;
        const float s = 2.0f - sqrtf(fmaxf(d2, 0.0f));
        const float sp = fmaxf(s, 0.0f) + log1pf(expf(-fabsf(s)));
        lsum += sp - ((labv[reg] == col) ? s : 0.0f);
      }
    }
  }
  for (int o = 32; o; o >>= 1) lsum += __shfl_xor(lsum, o, 64);
  if (lane == 0) sred[wid] = lsum;
  __syncthreads();
  if (t == 0) {
    float bs = 0.f;
#pragma unroll
    for (int w = 0; w < 8; ++w) bs += sred[w];
    atomicAdd(out, bs * (1.0f / ((float)B_N * (float)C_N)));
  }
}

// ---------------------------------------------------------------------------
extern "C" void kernel_launch(void* const* d_in, const int* in_sizes, int n_in,
                              void* d_out, int out_size, void* d_ws, size_t ws_size,
                              hipStream_t stream) {
  const float* emb_i = (const float*)d_in[0];
  const float* emb_j = (const float*)d_in[1];
  const int* labels = (const int*)d_in[2];
  float* out = (float*)d_out;

  char* ws = (char*)d_ws;
  unsigned short* z_j = (unsigned short*)ws;                         // 16 MB
  unsigned short* proto = (unsigned short*)(ws + (size_t)16777216);  // 2 MB
  float* p2 = (float*)(ws + (size_t)18874368);                       // 4 KB

  prep_kernel<<<dim3(C_N), 256, 0, stream>>>(emb_i, emb_j, labels, z_j,
                                             proto, p2, out);
  gemm_loss_kernel<<<dim3(B_N / BM, C_N / BN), 512, 0, stream>>>(z_j, proto,
                                                                 p2, labels, out);
}

// Round 2
// 146.097 us; speedup vs baseline: 1.0259x; 1.0259x over previous
//
#include <hip/hip_runtime.h>

#define B_N 8192
#define D_N 1024
#define C_N 1024
#define BM 256
#define BN 128
#define BK 64

typedef __attribute__((ext_vector_type(8))) __bf16 bf16x8;
typedef __attribute__((ext_vector_type(16))) float floatx16;

__device__ inline unsigned short f2bf(float f) {
  union { float f; unsigned int u; } cv; cv.f = f;
  unsigned int b = cv.u;
  unsigned int r = (b + 0x7FFFu + ((b >> 16) & 1u)) >> 16;  // RNE
  return (unsigned short)r;
}
__device__ inline float d4(const float4 a) {
  return a.x * a.x + a.y * a.y + a.z * a.z + a.w * a.w;
}
__device__ inline ushort4 pk4(const float4 v, const float s) {
  ushort4 u;
  u.x = f2bf(v.x * s); u.y = f2bf(v.y * s);
  u.z = f2bf(v.z * s); u.w = f2bf(v.w * s);
  return u;
}

// ---------------------------------------------------------------------------
// prep_kernel: unchanged (1024 fat blocks).
// ---------------------------------------------------------------------------
__global__ __launch_bounds__(256) void prep_kernel(
    const float* __restrict__ emb_i, const float* __restrict__ emb_j,
    const int* __restrict__ labels,
    unsigned short* __restrict__ z_j, unsigned short* __restrict__ proto,
    float* __restrict__ p2, float* __restrict__ out) {
  __shared__ float sx[4][8];
  __shared__ int list[8];
  __shared__ int scnt;

  const int t = threadIdx.x;
  const int lane = t & 63;
  const int wid = t >> 6;
  const int blk = blockIdx.x;

  if (t == 0) scnt = 0;
  if (blk == 0 && t == 0) out[0] = 0.0f;

#pragma unroll
  for (int it = 0; it < 2; ++it) {
    const int row = blk * 8 + it * 4 + wid;
    const float4* src = (const float4*)(emb_j + (size_t)row * D_N);
    const float4 v0 = src[lane], v1 = src[lane + 64];
    const float4 v2 = src[lane + 128], v3 = src[lane + 192];
    float ss = d4(v0) + d4(v1) + d4(v2) + d4(v3);
    for (int o = 32; o; o >>= 1) ss += __shfl_xor(ss, o, 64);
    const float inv = 1.0f / fmaxf(sqrtf(ss), 1e-12f);
    ushort4* dst = (ushort4*)(z_j + (size_t)row * D_N);
    dst[lane] = pk4(v0, inv);
    dst[lane + 64] = pk4(v1, inv);
    dst[lane + 128] = pk4(v2, inv);
    dst[lane + 192] = pk4(v3, inv);
  }

  const int c = blk;
  __syncthreads();
  const int4* lab4 = (const int4*)labels;
  for (int i = 0; i < 8; ++i) {
    const int q = i * 256 + t;
    const int4 L = lab4[q];
    const int base = q * 4;
    if (L.x == c) list[atomicAdd(&scnt, 1) & 7] = base;
    if (L.y == c) list[atomicAdd(&scnt, 1) & 7] = base + 1;
    if (L.z == c) list[atomicAdd(&scnt, 1) & 7] = base + 2;
    if (L.w == c) list[atomicAdd(&scnt, 1) & 7] = base + 3;
  }
  __syncthreads();

  const float* base = emb_i + wid * 256;
  float4 v[8];
  float ss[8];
#pragma unroll
  for (int k = 0; k < 8; ++k) {
    v[k] = ((const float4*)(base + (size_t)list[k] * D_N))[lane];
    ss[k] = d4(v[k]);
  }
#pragma unroll
  for (int k = 0; k < 8; ++k)
    for (int o = 32; o; o >>= 1) ss[k] += __shfl_xor(ss[k], o, 64);
  if (lane == 0) {
#pragma unroll
    for (int k = 0; k < 8; ++k) sx[wid][k] = ss[k];
  }
  __syncthreads();

  float4 a = make_float4(0.f, 0.f, 0.f, 0.f);
#pragma unroll
  for (int k = 0; k < 8; ++k) {
    const float tot = sx[0][k] + sx[1][k] + sx[2][k] + sx[3][k];
    const float iv = 1.0f / fmaxf(sqrtf(tot), 1e-12f);
    a.x += v[k].x * iv; a.y += v[k].y * iv;
    a.z += v[k].z * iv; a.w += v[k].w * iv;
  }
  a.x *= 0.125f; a.y *= 0.125f; a.z *= 0.125f; a.w *= 0.125f;

  float pp = d4(a);
  for (int o = 32; o; o >>= 1) pp += __shfl_xor(pp, o, 64);
  __syncthreads();
  if (lane == 0) sx[wid][0] = pp;
  __syncthreads();
  if (t == 0) p2[c] = sx[0][0] + sx[1][0] + sx[2][0] + sx[3][0];

  ((ushort4*)(proto + (size_t)c * D_N + wid * 256))[lane] = pk4(a, 1.0f);
}

// ---------------------------------------------------------------------------
// gemm_loss_kernel v5: same geometry as v4 (256x128, BK=64, 512 thr, 8 waves
// 4Mx2N, per-wave 64x64 = 2x2 of 32x32x16), but the K-loop is restructured
// into the 8-phase template cadence (T3+T4+T5): 2 phases per K-tile, each
// phase = {8 ds_read_b128 (2 kk slices, 4 independent MFMA chains) +
// 3 global_load_lds issues, lgkmcnt(0)+sched_barrier, setprio(1), 8 MFMA,
// setprio(0), s_barrier}. One vmcnt(6)+barrier gate per K-tile (counted,
// never 0 until the peeled tail). 3-deep LDS buffers (3 x 48KB = 144KB).
//
// vmcnt ledger (6 GLOADs/wave/K-tile, 3 issued per phase x 2 phases):
//   prologue: s0,s1 -> 12 outstanding
//   iter kt (0..13): vmcnt(6) => s_kt landed; barrier; phases issue s_(kt+2)
//                    (back to 12 by iter end)
//   kt=14: vmcnt(6) => s14 landed; no issues
//   kt=15: vmcnt(0) => s15 landed
// Write-after-read: buffer (kt+2)%3 last read in iter kt-1's phases, all
// before iter kt-1's final phase barrier; GLOADs for kt+2 issue after it.
// Read-after-write: per-wave vmcnt + all-waves barrier at iter top.
// ---------------------------------------------------------------------------
#define GLOAD(gp, lp)                                                        \
  __builtin_amdgcn_global_load_lds(                                          \
      (const __attribute__((address_space(1))) void*)(gp),                   \
      (__attribute__((address_space(3))) void*)(lp), 16, 0, 0)

__global__ __launch_bounds__(512) void gemm_loss_kernel(
    const unsigned short* __restrict__ Zj,   // [B,D] bf16
    const unsigned short* __restrict__ P,    // [C,D] bf16
    const float* __restrict__ p2,            // [C]
    const int* __restrict__ labels,          // [B]
    float* __restrict__ out) {               // scalar (zeroed by prep)
  // buffer = A(256x64) 32KB + B(128x64) 16KB = 24576 ushorts; x3 = 144KB
  __shared__ __align__(16) unsigned short lds[3 * 24576];
  __shared__ float sred[8];

  const int t = threadIdx.x;
  const int lane = t & 63;
  const int wid = t >> 6;
  const int wm = (wid >> 1) * 64;   // 4 waves in M
  const int wn = (wid & 1) * 64;    // 2 waves in N
  const int bm = blockIdx.x;
  const int bn = blockIdx.y;

  floatx16 acc[2][2];
#pragma unroll
  for (int i = 0; i < 2; ++i)
#pragma unroll
    for (int j = 0; j < 2; ++j)
      for (int r = 0; r < 16; ++r) acc[i][j][r] = 0.f;

  // staging: pass = 512 thr x 16B = 8KB = 64 rows x 128B. thread t -> row
  // (t>>3) (+64/pass), chunk slot t&7, fetching global chunk (t&7)^(row&7).
  const int srow = t >> 3;
  const int g = (t & 7) ^ (srow & 7);
  const unsigned short* Ag = Zj + (size_t)(bm * BM + srow) * D_N + g * 8;
  const unsigned short* Bg = P + (size_t)(bn * BN + srow) * D_N + g * 8;
  unsigned short* const Al0 = (unsigned short*)lds + t * 8;
  unsigned short* const Bl0 = (unsigned short*)lds + 16384 + t * 8;

  // ds_read row bases (ushort units), row stride BK=64
  const int ar0 = (wm + (lane & 31)) * BK;
  const int ar1 = ar0 + 32 * BK;
  const int br0 = 16384 + (wn + (lane & 31)) * BK;
  const int br1 = br0 + 32 * BK;
  const int h = lane >> 5;  // K-half selector
  const int q = lane & 7;   // row&7 for swizzle inverse

#define STAGE_A(bi, k2)                                                      \
  do {                                                                       \
    unsigned short* _al = Al0 + (bi) * 24576;                                \
    GLOAD(Ag + (size_t)0 * 64 * D_N + (k2), _al + 0 * 4096);                 \
    GLOAD(Ag + (size_t)1 * 64 * D_N + (k2), _al + 1 * 4096);                 \
    GLOAD(Ag + (size_t)2 * 64 * D_N + (k2), _al + 2 * 4096);                 \
  } while (0)
#define STAGE_B(bi, k2)                                                      \
  do {                                                                       \
    unsigned short* _al = Al0 + (bi) * 24576;                                \
    unsigned short* _bl = Bl0 + (bi) * 24576;                                \
    GLOAD(Ag + (size_t)3 * 64 * D_N + (k2), _al + 3 * 4096);                 \
    GLOAD(Bg + (size_t)0 * 64 * D_N + (k2), _bl + 0 * 4096);                 \
    GLOAD(Bg + (size_t)1 * 64 * D_N + (k2), _bl + 1 * 4096);                 \
  } while (0)
#define NOGL ((void)0)

  // One phase: 2 kk slices (8 ds_read_b128), GLOAD issues, MFMA cluster.
  // 4 independent acc chains of length 2 -> no MFMA dependency stall.
#define PHASE(bi, kkb, GL)                                                   \
  {                                                                          \
    const unsigned short* Lb = (const unsigned short*)lds + (bi) * 24576;    \
    const int s0 = ((((kkb) + 0) * 2 + h) ^ q) << 3;                         \
    const int s1 = ((((kkb) + 1) * 2 + h) ^ q) << 3;                         \
    bf16x8 a0k0 = *(const bf16x8*)(Lb + ar0 + s0);                           \
    bf16x8 a1k0 = *(const bf16x8*)(Lb + ar1 + s0);                           \
    bf16x8 b0k0 = *(const bf16x8*)(Lb + br0 + s0);                           \
    bf16x8 b1k0 = *(const bf16x8*)(Lb + br1 + s0);                           \
    bf16x8 a0k1 = *(const bf16x8*)(Lb + ar0 + s1);                           \
    bf16x8 a1k1 = *(const bf16x8*)(Lb + ar1 + s1);                           \
    bf16x8 b0k1 = *(const bf16x8*)(Lb + br0 + s1);                           \
    bf16x8 b1k1 = *(const bf16x8*)(Lb + br1 + s1);                           \
    GL;                                                                      \
    asm volatile("s_waitcnt lgkmcnt(0)" ::: "memory");                       \
    __builtin_amdgcn_sched_barrier(0);                                       \
    __builtin_amdgcn_s_setprio(1);                                           \
    acc[0][0] = __builtin_amdgcn_mfma_f32_32x32x16_bf16(a0k0, b0k0, acc[0][0], 0, 0, 0); \
    acc[0][1] = __builtin_amdgcn_mfma_f32_32x32x16_bf16(a0k0, b1k0, acc[0][1], 0, 0, 0); \
    acc[1][0] = __builtin_amdgcn_mfma_f32_32x32x16_bf16(a1k0, b0k0, acc[1][0], 0, 0, 0); \
    acc[1][1] = __builtin_amdgcn_mfma_f32_32x32x16_bf16(a1k0, b1k0, acc[1][1], 0, 0, 0); \
    acc[0][0] = __builtin_amdgcn_mfma_f32_32x32x16_bf16(a0k1, b0k1, acc[0][0], 0, 0, 0); \
    acc[0][1] = __builtin_amdgcn_mfma_f32_32x32x16_bf16(a0k1, b1k1, acc[0][1], 0, 0, 0); \
    acc[1][0] = __builtin_amdgcn_mfma_f32_32x32x16_bf16(a1k1, b0k1, acc[1][0], 0, 0, 0); \
    acc[1][1] = __builtin_amdgcn_mfma_f32_32x32x16_bf16(a1k1, b1k1, acc[1][1], 0, 0, 0); \
    __builtin_amdgcn_s_setprio(0);                                           \
    __builtin_amdgcn_sched_barrier(0);                                       \
    __builtin_amdgcn_s_barrier();                                            \
  }

  // prologue: fill buffers 0 and 1 (K-tiles 0, 1) -> 12 outstanding
  STAGE_A(0, 0); STAGE_B(0, 0);
  STAGE_A(1, BK); STAGE_B(1, BK);

  int cur = 0;
  for (int kt = 0; kt < 14; ++kt) {
    const int nb = (cur == 0) ? 2 : cur - 1;  // (cur+2)%3
    const int k2 = (kt + 2) * BK;
    asm volatile("s_waitcnt vmcnt(6)" ::: "memory");
    __builtin_amdgcn_s_barrier();
    PHASE(cur, 0, STAGE_A(nb, k2));
    PHASE(cur, 2, STAGE_B(nb, k2));
    cur = (cur == 2) ? 0 : cur + 1;
  }
  // kt = 14
  asm volatile("s_waitcnt vmcnt(6)" ::: "memory");
  __builtin_amdgcn_s_barrier();
  PHASE(cur, 0, NOGL);
  PHASE(cur, 2, NOGL);
  cur = (cur == 2) ? 0 : cur + 1;
  // kt = 15
  asm volatile("s_waitcnt vmcnt(0)" ::: "memory");
  __builtin_amdgcn_s_barrier();
  PHASE(cur, 0, NOGL);
  PHASE(cur, 2, NOGL);

  // epilogue: 32x32 C/D layout col=lane&31, row=(reg&3)+8*(reg>>2)+4*(lane>>5)
  const int colbase = bn * BN + wn + (lane & 31);
  float lsum = 0.f;
#pragma unroll
  for (int mb = 0; mb < 2; ++mb) {
    const int rowbase = bm * BM + wm + mb * 32 + 4 * h;
    int labv[16];
#pragma unroll
    for (int reg = 0; reg < 16; ++reg)
      labv[reg] = labels[rowbase + (reg & 3) + 8 * (reg >> 2)];
#pragma unroll
    for (int nb2 = 0; nb2 < 2; ++nb2) {
      const int col = colbase + nb2 * 32;
      const float p2c = p2[col];
#pragma unroll
      for (int reg = 0; reg < 16; ++reg) {
        const float dot = acc[mb][nb2][reg];
        const float d2 = 1.0f + p2c - 2.0f * dot;
        const float s = 2.0f - sqrtf(fmaxf(d2, 0.0f));
        const float sp = fmaxf(s, 0.0f) + log1pf(expf(-fabsf(s)));
        lsum += sp - ((labv[reg] == col) ? s : 0.0f);
      }
    }
  }
  for (int o = 32; o; o >>= 1) lsum += __shfl_xor(lsum, o, 64);
  if (lane == 0) sred[wid] = lsum;
  __syncthreads();
  if (t == 0) {
    float bs = 0.f;
#pragma unroll
    for (int w = 0; w < 8; ++w) bs += sred[w];
    atomicAdd(out, bs * (1.0f / ((float)B_N * (float)C_N)));
  }
}

// ---------------------------------------------------------------------------
extern "C" void kernel_launch(void* const* d_in, const int* in_sizes, int n_in,
                              void* d_out, int out_size, void* d_ws, size_t ws_size,
                              hipStream_t stream) {
  const float* emb_i = (const float*)d_in[0];
  const float* emb_j = (const float*)d_in[1];
  const int* labels = (const int*)d_in[2];
  float* out = (float*)d_out;

  char* ws = (char*)d_ws;
  unsigned short* z_j = (unsigned short*)ws;                         // 16 MB
  unsigned short* proto = (unsigned short*)(ws + (size_t)16777216);  // 2 MB
  float* p2 = (float*)(ws + (size_t)18874368);                       // 4 KB

  prep_kernel<<<dim3(C_N), 256, 0, stream>>>(emb_i, emb_j, labels, z_j,
                                             proto, p2, out);
  gemm_loss_kernel<<<dim3(B_N / BM, C_N / BN), 512, 0, stream>>>(z_j, proto,
                                                                 p2, labels, out);
}

// Round 3
// 131.216 us; speedup vs baseline: 1.1422x; 1.1134x over previous
//
#include <hip/hip_runtime.h>

#define B_N 8192
#define D_N 1024
#define C_N 1024
#define BM 256
#define BN 128
#define BK 64

typedef __attribute__((ext_vector_type(8))) __bf16 bf16x8;
typedef __attribute__((ext_vector_type(16))) float floatx16;

__device__ inline unsigned short f2bf(float f) {
  union { float f; unsigned int u; } cv; cv.f = f;
  unsigned int b = cv.u;
  unsigned int r = (b + 0x7FFFu + ((b >> 16) & 1u)) >> 16;  // RNE
  return (unsigned short)r;
}
__device__ inline float d4(const float4 a) {
  return a.x * a.x + a.y * a.y + a.z * a.z + a.w * a.w;
}
__device__ inline ushort4 pk4(const float4 v, const float s) {
  ushort4 u;
  u.x = f2bf(v.x * s); u.y = f2bf(v.y * s);
  u.z = f2bf(v.z * s); u.w = f2bf(v.w * s);
  return u;
}

// ---------------------------------------------------------------------------
// prep_a: blocks [0,2048): normalize emb_j -> z_j bf16 (1 row per wave).
//         blocks [2048,2056): build inverted label index idx[c*8+slot]=row
//         for class range [ib*128,(ib+1)*128) via shared counters.
//         (each class appears exactly 8x by construction)
// ---------------------------------------------------------------------------
__global__ __launch_bounds__(256) void prep_a(
    const float* __restrict__ emb_j, const int* __restrict__ labels,
    unsigned short* __restrict__ z_j, int* __restrict__ idx,
    float* __restrict__ out) {
  const int t = threadIdx.x;
  const int lane = t & 63;
  const int wid = t >> 6;
  const int b = blockIdx.x;

  if (b == 0 && t == 0) out[0] = 0.0f;

  if (b < 2048) {
    const int row = b * 4 + wid;
    const float4* src = (const float4*)(emb_j + (size_t)row * D_N);
    const float4 v0 = src[lane], v1 = src[lane + 64];
    const float4 v2 = src[lane + 128], v3 = src[lane + 192];
    float ss = d4(v0) + d4(v1) + d4(v2) + d4(v3);
    for (int o = 32; o; o >>= 1) ss += __shfl_xor(ss, o, 64);
    const float inv = 1.0f / fmaxf(sqrtf(ss), 1e-12f);
    ushort4* dst = (ushort4*)(z_j + (size_t)row * D_N);
    dst[lane] = pk4(v0, inv);
    dst[lane + 64] = pk4(v1, inv);
    dst[lane + 128] = pk4(v2, inv);
    dst[lane + 192] = pk4(v3, inv);
  } else {
    __shared__ int cnt[128];
    const int ib = b - 2048;
    for (int i = t; i < 128; i += 256) cnt[i] = 0;
    __syncthreads();
    const int4* lab4 = (const int4*)labels;
    for (int i = 0; i < 8; ++i) {
      const int qv = i * 256 + t;
      const int4 L = lab4[qv];
      const int base = qv * 4;
      if ((L.x >> 7) == ib) idx[L.x * 8 + atomicAdd(&cnt[L.x & 127], 1)] = base;
      if ((L.y >> 7) == ib) idx[L.y * 8 + atomicAdd(&cnt[L.y & 127], 1)] = base + 1;
      if ((L.z >> 7) == ib) idx[L.z * 8 + atomicAdd(&cnt[L.z & 127], 1)] = base + 2;
      if ((L.w >> 7) == ib) idx[L.w * 8 + atomicAdd(&cnt[L.w & 127], 1)] = base + 3;
    }
  }
}

// ---------------------------------------------------------------------------
// prep_b: one block per class c. Gather the 8 emb_i rows from idx, normalize
// each (cross-wave norm via LDS: each wave owns a 256-col slice), average,
// write proto row (bf16) and p2[c] = ||proto_c||^2.
// ---------------------------------------------------------------------------
__global__ __launch_bounds__(256) void prep_b(
    const float* __restrict__ emb_i, const int* __restrict__ idx,
    unsigned short* __restrict__ proto, float* __restrict__ p2) {
  __shared__ float sx[4][8];
  const int t = threadIdx.x;
  const int lane = t & 63;
  const int wid = t >> 6;
  const int c = blockIdx.x;

  int li[8];
#pragma unroll
  for (int k = 0; k < 8; ++k) li[k] = idx[c * 8 + k];

  const float* base = emb_i + wid * 256;
  float4 v[8];
  float ss[8];
#pragma unroll
  for (int k = 0; k < 8; ++k) {
    v[k] = ((const float4*)(base + (size_t)li[k] * D_N))[lane];
    ss[k] = d4(v[k]);
  }
#pragma unroll
  for (int k = 0; k < 8; ++k)
    for (int o = 32; o; o >>= 1) ss[k] += __shfl_xor(ss[k], o, 64);
  if (lane == 0) {
#pragma unroll
    for (int k = 0; k < 8; ++k) sx[wid][k] = ss[k];
  }
  __syncthreads();

  float4 a = make_float4(0.f, 0.f, 0.f, 0.f);
#pragma unroll
  for (int k = 0; k < 8; ++k) {
    const float tot = sx[0][k] + sx[1][k] + sx[2][k] + sx[3][k];
    const float iv = 1.0f / fmaxf(sqrtf(tot), 1e-12f);
    a.x += v[k].x * iv; a.y += v[k].y * iv;
    a.z += v[k].z * iv; a.w += v[k].w * iv;
  }
  a.x *= 0.125f; a.y *= 0.125f; a.z *= 0.125f; a.w *= 0.125f;

  float pp = d4(a);
  for (int o = 32; o; o >>= 1) pp += __shfl_xor(pp, o, 64);
  __syncthreads();
  if (lane == 0) sx[wid][0] = pp;
  __syncthreads();
  if (t == 0) p2[c] = sx[0][0] + sx[1][0] + sx[2][0] + sx[3][0];

  ((ushort4*)(proto + (size_t)c * D_N + wid * 256))[lane] = pk4(a, 1.0f);
}

// ---------------------------------------------------------------------------
// gemm_loss_kernel v6: R2's verified phase-interleaved pipeline (256x128,
// BK=64, 512 thr, 8 waves 4Mx2N, 3-deep LDS, counted vmcnt(6)), with a
// cheap epilogue: log1pf(expf(.)) -> __logf(1+__expf(.)) (2 HW transcendentals
// instead of libm expansions).
// ---------------------------------------------------------------------------
#define GLOAD(gp, lp)                                                        \
  __builtin_amdgcn_global_load_lds(                                          \
      (const __attribute__((address_space(1))) void*)(gp),                   \
      (__attribute__((address_space(3))) void*)(lp), 16, 0, 0)

__global__ __launch_bounds__(512) void gemm_loss_kernel(
    const unsigned short* __restrict__ Zj,   // [B,D] bf16
    const unsigned short* __restrict__ P,    // [C,D] bf16
    const float* __restrict__ p2,            // [C]
    const int* __restrict__ labels,          // [B]
    float* __restrict__ out) {               // scalar (zeroed by prep_a)
  __shared__ __align__(16) unsigned short lds[3 * 24576];
  __shared__ float sred[8];

  const int t = threadIdx.x;
  const int lane = t & 63;
  const int wid = t >> 6;
  const int wm = (wid >> 1) * 64;
  const int wn = (wid & 1) * 64;
  const int bm = blockIdx.x;
  const int bn = blockIdx.y;

  floatx16 acc[2][2];
#pragma unroll
  for (int i = 0; i < 2; ++i)
#pragma unroll
    for (int j = 0; j < 2; ++j)
      for (int r = 0; r < 16; ++r) acc[i][j][r] = 0.f;

  const int srow = t >> 3;
  const int g = (t & 7) ^ (srow & 7);
  const unsigned short* Ag = Zj + (size_t)(bm * BM + srow) * D_N + g * 8;
  const unsigned short* Bg = P + (size_t)(bn * BN + srow) * D_N + g * 8;
  unsigned short* const Al0 = (unsigned short*)lds + t * 8;
  unsigned short* const Bl0 = (unsigned short*)lds + 16384 + t * 8;

  const int ar0 = (wm + (lane & 31)) * BK;
  const int ar1 = ar0 + 32 * BK;
  const int br0 = 16384 + (wn + (lane & 31)) * BK;
  const int br1 = br0 + 32 * BK;
  const int h = lane >> 5;
  const int q = lane & 7;

#define STAGE_A(bi, k2)                                                      \
  do {                                                                       \
    unsigned short* _al = Al0 + (bi) * 24576;                                \
    GLOAD(Ag + (size_t)0 * 64 * D_N + (k2), _al + 0 * 4096);                 \
    GLOAD(Ag + (size_t)1 * 64 * D_N + (k2), _al + 1 * 4096);                 \
    GLOAD(Ag + (size_t)2 * 64 * D_N + (k2), _al + 2 * 4096);                 \
  } while (0)
#define STAGE_B(bi, k2)                                                      \
  do {                                                                       \
    unsigned short* _al = Al0 + (bi) * 24576;                                \
    unsigned short* _bl = Bl0 + (bi) * 24576;                                \
    GLOAD(Ag + (size_t)3 * 64 * D_N + (k2), _al + 3 * 4096);                 \
    GLOAD(Bg + (size_t)0 * 64 * D_N + (k2), _bl + 0 * 4096);                 \
    GLOAD(Bg + (size_t)1 * 64 * D_N + (k2), _bl + 1 * 4096);                 \
  } while (0)
#define NOGL ((void)0)

#define PHASE(bi, kkb, GL)                                                   \
  {                                                                          \
    const unsigned short* Lb = (const unsigned short*)lds + (bi) * 24576;    \
    const int s0 = ((((kkb) + 0) * 2 + h) ^ q) << 3;                         \
    const int s1 = ((((kkb) + 1) * 2 + h) ^ q) << 3;                         \
    bf16x8 a0k0 = *(const bf16x8*)(Lb + ar0 + s0);                           \
    bf16x8 a1k0 = *(const bf16x8*)(Lb + ar1 + s0);                           \
    bf16x8 b0k0 = *(const bf16x8*)(Lb + br0 + s0);                           \
    bf16x8 b1k0 = *(const bf16x8*)(Lb + br1 + s0);                           \
    bf16x8 a0k1 = *(const bf16x8*)(Lb + ar0 + s1);                           \
    bf16x8 a1k1 = *(const bf16x8*)(Lb + ar1 + s1);                           \
    bf16x8 b0k1 = *(const bf16x8*)(Lb + br0 + s1);                           \
    bf16x8 b1k1 = *(const bf16x8*)(Lb + br1 + s1);                           \
    GL;                                                                      \
    asm volatile("s_waitcnt lgkmcnt(0)" ::: "memory");                       \
    __builtin_amdgcn_sched_barrier(0);                                       \
    __builtin_amdgcn_s_setprio(1);                                           \
    acc[0][0] = __builtin_amdgcn_mfma_f32_32x32x16_bf16(a0k0, b0k0, acc[0][0], 0, 0, 0); \
    acc[0][1] = __builtin_amdgcn_mfma_f32_32x32x16_bf16(a0k0, b1k0, acc[0][1], 0, 0, 0); \
    acc[1][0] = __builtin_amdgcn_mfma_f32_32x32x16_bf16(a1k0, b0k0, acc[1][0], 0, 0, 0); \
    acc[1][1] = __builtin_amdgcn_mfma_f32_32x32x16_bf16(a1k0, b1k0, acc[1][1], 0, 0, 0); \
    acc[0][0] = __builtin_amdgcn_mfma_f32_32x32x16_bf16(a0k1, b0k1, acc[0][0], 0, 0, 0); \
    acc[0][1] = __builtin_amdgcn_mfma_f32_32x32x16_bf16(a0k1, b1k1, acc[0][1], 0, 0, 0); \
    acc[1][0] = __builtin_amdgcn_mfma_f32_32x32x16_bf16(a1k1, b0k1, acc[1][0], 0, 0, 0); \
    acc[1][1] = __builtin_amdgcn_mfma_f32_32x32x16_bf16(a1k1, b1k1, acc[1][1], 0, 0, 0); \
    __builtin_amdgcn_s_setprio(0);                                           \
    __builtin_amdgcn_sched_barrier(0);                                       \
    __builtin_amdgcn_s_barrier();                                            \
  }

  STAGE_A(0, 0); STAGE_B(0, 0);
  STAGE_A(1, BK); STAGE_B(1, BK);

  int cur = 0;
  for (int kt = 0; kt < 14; ++kt) {
    const int nb = (cur == 0) ? 2 : cur - 1;  // (cur+2)%3
    const int k2 = (kt + 2) * BK;
    asm volatile("s_waitcnt vmcnt(6)" ::: "memory");
    __builtin_amdgcn_s_barrier();
    PHASE(cur, 0, STAGE_A(nb, k2));
    PHASE(cur, 2, STAGE_B(nb, k2));
    cur = (cur == 2) ? 0 : cur + 1;
  }
  asm volatile("s_waitcnt vmcnt(6)" ::: "memory");
  __builtin_amdgcn_s_barrier();
  PHASE(cur, 0, NOGL);
  PHASE(cur, 2, NOGL);
  cur = (cur == 2) ? 0 : cur + 1;
  asm volatile("s_waitcnt vmcnt(0)" ::: "memory");
  __builtin_amdgcn_s_barrier();
  PHASE(cur, 0, NOGL);
  PHASE(cur, 2, NOGL);

  // epilogue: C/D layout col=lane&31, row=(reg&3)+8*(reg>>2)+4*(lane>>5)
  const int colbase = bn * BN + wn + (lane & 31);
  float lsum = 0.f;
#pragma unroll
  for (int mb = 0; mb < 2; ++mb) {
    const int rowbase = bm * BM + wm + mb * 32 + 4 * h;
    int labv[16];
#pragma unroll
    for (int reg = 0; reg < 16; ++reg)
      labv[reg] = labels[rowbase + (reg & 3) + 8 * (reg >> 2)];
#pragma unroll
    for (int nb2 = 0; nb2 < 2; ++nb2) {
      const int col = colbase + nb2 * 32;
      const float p2c = p2[col];
#pragma unroll
      for (int reg = 0; reg < 16; ++reg) {
        const float dot = acc[mb][nb2][reg];
        const float d2 = 1.0f + p2c - 2.0f * dot;
        const float s = 2.0f - sqrtf(fmaxf(d2, 0.0f));
        // softplus(s) = max(s,0) + log1p(exp(-|s|)); fast HW transcendentals
        const float e = __expf(-fabsf(s));
        lsum += fmaxf(s, 0.0f) + __logf(1.0f + e) - ((labv[reg] == col) ? s : 0.0f);
      }
    }
  }
  for (int o = 32; o; o >>= 1) lsum += __shfl_xor(lsum, o, 64);
  if (lane == 0) sred[wid] = lsum;
  __syncthreads();
  if (t == 0) {
    float bs = 0.f;
#pragma unroll
    for (int w = 0; w < 8; ++w) bs += sred[w];
    atomicAdd(out, bs * (1.0f / ((float)B_N * (float)C_N)));
  }
}

// ---------------------------------------------------------------------------
extern "C" void kernel_launch(void* const* d_in, const int* in_sizes, int n_in,
                              void* d_out, int out_size, void* d_ws, size_t ws_size,
                              hipStream_t stream) {
  const float* emb_i = (const float*)d_in[0];
  const float* emb_j = (const float*)d_in[1];
  const int* labels = (const int*)d_in[2];
  float* out = (float*)d_out;

  char* ws = (char*)d_ws;
  unsigned short* z_j = (unsigned short*)ws;                         // 16 MB
  unsigned short* proto = (unsigned short*)(ws + (size_t)16777216);  // 2 MB
  float* p2 = (float*)(ws + (size_t)18874368);                       // 4 KB
  int* idx = (int*)(ws + (size_t)18878464);                          // 32 KB

  prep_a<<<dim3(2056), 256, 0, stream>>>(emb_j, labels, z_j, idx, out);
  prep_b<<<dim3(C_N), 256, 0, stream>>>(emb_i, idx, proto, p2);
  gemm_loss_kernel<<<dim3(B_N / BM, C_N / BN), 512, 0, stream>>>(z_j, proto,
                                                                 p2, labels, out);
}